// Round 4
// baseline (3184.826 us; speedup 1.0000x reference)
//
#include <hip/hip_runtime.h>
#include <hip/hip_bf16.h>

#define HDIM 128
#define G3 384          // 3*H
#define EDIM 300
#define BATCH 64
#define LSTO 1024
#define QLEN 32
#define NSENT 16

typedef float4 f4;

__device__ __forceinline__ float sigmf(float x) { return 1.0f / (1.0f + __expf(-x)); }
__device__ __forceinline__ float tanhfast(float x) {
    float e = __expf(-2.0f * x);
    return (1.0f - e) / (1.0f + e);
}

// ---------------------------------------------------------------------------
// K1: gi[row][g] = b_ih[g] + emb[tok[row]] . w_ih[g]   (K = 300), bf16 out
// 32 rows per WG staged in LDS; 192 threads, each handles g and g+192.
// ---------------------------------------------------------------------------
__global__ __launch_bounds__(192) void k_gi_gather(
    const int* __restrict__ toks, int nrows,
    const float* __restrict__ emb,
    const float* __restrict__ w_ih, const float* __restrict__ b_ih,
    __hip_bfloat16* __restrict__ gi)
{
    __shared__ alignas(16) float a_lds[32 * EDIM];
    int tid = threadIdx.x;
    int rowbase = blockIdx.x * 32;

    for (int i = tid; i < 32 * 75; i += 192) {   // 75 = 300/4
        int r = i / 75, e4 = i - r * 75;
        int row = rowbase + r;
        int tok = (row < nrows) ? toks[row] : 0;
        f4 v = *reinterpret_cast<const f4*>(emb + (size_t)tok * EDIM + e4 * 4);
        *reinterpret_cast<f4*>(a_lds + r * EDIM + e4 * 4) = v;
    }
    __syncthreads();

    int g0 = tid, g1 = tid + 192;
    float acc0[32], acc1[32];
#pragma unroll
    for (int r = 0; r < 32; r++) { acc0[r] = 0.f; acc1[r] = 0.f; }

    const float* w0p = w_ih + (size_t)g0 * EDIM;
    const float* w1p = w_ih + (size_t)g1 * EDIM;
    for (int e4 = 0; e4 < 75; ++e4) {
        f4 w0 = *reinterpret_cast<const f4*>(w0p + e4 * 4);
        f4 w1 = *reinterpret_cast<const f4*>(w1p + e4 * 4);
#pragma unroll
        for (int r = 0; r < 32; r++) {
            f4 a = *reinterpret_cast<const f4*>(a_lds + r * EDIM + e4 * 4);
            acc0[r] += a.x * w0.x + a.y * w0.y + a.z * w0.z + a.w * w0.w;
            acc1[r] += a.x * w1.x + a.y * w1.y + a.z * w1.z + a.w * w1.w;
        }
    }
    float bb0 = b_ih[g0], bb1 = b_ih[g1];
    for (int r = 0; r < 32; r++) {
        int row = rowbase + r;
        if (row < nrows) {
            gi[(size_t)row * G3 + g0] = __float2bfloat16(acc0[r] + bb0);
            gi[(size_t)row * G3 + g1] = __float2bfloat16(acc1[r] + bb1);
        }
    }
}

// ---------------------------------------------------------------------------
// K1b: dense variant, K = 128 (episodic gi from sents)
// ---------------------------------------------------------------------------
__global__ __launch_bounds__(192) void k_gi_dense(
    const float* __restrict__ x, int nrows,
    const float* __restrict__ w_ih, const float* __restrict__ b_ih,
    __hip_bfloat16* __restrict__ gi)
{
    __shared__ alignas(16) float a_lds[32 * HDIM];
    int tid = threadIdx.x;
    int rowbase = blockIdx.x * 32;

    for (int i = tid; i < 32 * 32; i += 192) {   // 32 = 128/4
        int r = i >> 5, e4 = i & 31;
        int row = rowbase + r;
        f4 v;
        if (row < nrows) v = *reinterpret_cast<const f4*>(x + (size_t)row * HDIM + e4 * 4);
        else { v.x = v.y = v.z = v.w = 0.f; }
        *reinterpret_cast<f4*>(a_lds + r * HDIM + e4 * 4) = v;
    }
    __syncthreads();

    int g0 = tid, g1 = tid + 192;
    float acc0[32], acc1[32];
#pragma unroll
    for (int r = 0; r < 32; r++) { acc0[r] = 0.f; acc1[r] = 0.f; }

    const float* w0p = w_ih + (size_t)g0 * HDIM;
    const float* w1p = w_ih + (size_t)g1 * HDIM;
    for (int e4 = 0; e4 < 32; ++e4) {
        f4 w0 = *reinterpret_cast<const f4*>(w0p + e4 * 4);
        f4 w1 = *reinterpret_cast<const f4*>(w1p + e4 * 4);
#pragma unroll
        for (int r = 0; r < 32; r++) {
            f4 a = *reinterpret_cast<const f4*>(a_lds + r * HDIM + e4 * 4);
            acc0[r] += a.x * w0.x + a.y * w0.y + a.z * w0.z + a.w * w0.w;
            acc1[r] += a.x * w1.x + a.y * w1.y + a.z * w1.z + a.w * w1.w;
        }
    }
    float bb0 = b_ih[g0], bb1 = b_ih[g1];
    for (int r = 0; r < 32; r++) {
        int row = rowbase + r;
        if (row < nrows) {
            gi[(size_t)row * G3 + g0] = __float2bfloat16(acc0[r] + bb0);
            gi[(size_t)row * G3 + g1] = __float2bfloat16(acc1[r] + bb1);
        }
    }
}

// ---------------------------------------------------------------------------
// K2: sequential GRU scan, one workgroup per batch element.
// 192 threads; thread holds w_hh rows g and g+192 in VGPRs (256 f32 regs).
// MODE 0: stories (write sents at masked positions)
// MODE 1: questions (write q_vec at position qi)
// MODE 2: episodic (gate-interpolated update, write final h)
// ---------------------------------------------------------------------------
template <int MODE>
__global__ __launch_bounds__(192, 1) void k_scan(
    const __hip_bfloat16* __restrict__ gi,   // [BATCH*T][384]
    int T,
    const float* __restrict__ w_hh, const float* __restrict__ b_hh,
    const int* __restrict__ mask,            // MODE 0
    float* __restrict__ sents,               // MODE 0
    const int* __restrict__ qtoks,           // MODE 1
    float* __restrict__ qv_out,              // MODE 1 (d_out)
    float* __restrict__ q_ws,                // MODE 1
    const float* __restrict__ gates,         // MODE 2
    float* __restrict__ h_out,               // MODE 2 (mem ws)
    float* __restrict__ ep_out)              // MODE 2 (d_out, nullable)
{
    __shared__ alignas(16) float h_lds[HDIM];
    __shared__ float gh_lds[G3];

    int tid = threadIdx.x;
    int b = blockIdx.x;
    int g0 = tid, g1 = tid + 192;

    float w0[HDIM], w1[HDIM];
#pragma unroll
    for (int k4 = 0; k4 < 32; k4++) {
        f4 a = *reinterpret_cast<const f4*>(w_hh + (size_t)g0 * HDIM + k4 * 4);
        w0[4 * k4 + 0] = a.x; w0[4 * k4 + 1] = a.y; w0[4 * k4 + 2] = a.z; w0[4 * k4 + 3] = a.w;
        f4 c = *reinterpret_cast<const f4*>(w_hh + (size_t)g1 * HDIM + k4 * 4);
        w1[4 * k4 + 0] = c.x; w1[4 * k4 + 1] = c.y; w1[4 * k4 + 2] = c.z; w1[4 * k4 + 3] = c.w;
    }
    float bb0 = b_hh[g0], bb1 = b_hh[g1];

    if (tid < HDIM) h_lds[tid] = 0.f;

    int qi = QLEN - 1;
    if (MODE == 1) {
        for (int t2 = QLEN - 2; t2 >= 0; --t2)
            if (qtoks[b * QLEN + t2 + 1] == 0) qi = t2;
    }
    int scnt = 0;
    __syncthreads();

    const __hip_bfloat16* gib = gi + (size_t)b * T * G3;

    for (int t = 0; t < T; ++t) {
        float acc0 = bb0, acc1 = bb1;
#pragma unroll
        for (int k4 = 0; k4 < 32; k4++) {
            f4 hv = *reinterpret_cast<const f4*>(h_lds + 4 * k4);
            acc0 += hv.x * w0[4 * k4 + 0] + hv.y * w0[4 * k4 + 1] +
                    hv.z * w0[4 * k4 + 2] + hv.w * w0[4 * k4 + 3];
            acc1 += hv.x * w1[4 * k4 + 0] + hv.y * w1[4 * k4 + 1] +
                    hv.z * w1[4 * k4 + 2] + hv.w * w1[4 * k4 + 3];
        }
        gh_lds[g0] = acc0;
        gh_lds[g1] = acc1;
        __syncthreads();

        if (tid < HDIM) {
            int j = tid;
            const __hip_bfloat16* gr = gib + (size_t)t * G3;
            float gi_r = __bfloat162float(gr[j]);
            float gi_z = __bfloat162float(gr[HDIM + j]);
            float gi_n = __bfloat162float(gr[2 * HDIM + j]);
            float r = sigmf(gi_r + gh_lds[j]);
            float z = sigmf(gi_z + gh_lds[HDIM + j]);
            float n = tanhfast(gi_n + r * gh_lds[2 * HDIM + j]);
            float hprev = h_lds[j];
            float hn = (1.f - z) * n + z * hprev;
            if (MODE == 2) {
                float w = gates[b * NSENT + t];
                hn = w * hn + (1.f - w) * hprev;
            }
            h_lds[j] = hn;

            if (MODE == 0) {
                int m = mask[b * LSTO + t];
                if (m) {
                    if (scnt < NSENT)
                        sents[((size_t)b * NSENT + scnt) * HDIM + j] = hn;
                    scnt++;
                }
            }
            if (MODE == 1 && t == qi) {
                qv_out[b * HDIM + j] = hn;
                q_ws[b * HDIM + j] = hn;
            }
            if (MODE == 2 && t == T - 1) {
                h_out[b * HDIM + j] = hn;
                if (ep_out) ep_out[b * HDIM + j] = hn;
            }
        }
        __syncthreads();
    }
}

// ---------------------------------------------------------------------------
// K3: attention gates.  WG per batch, 128 threads = (16 t) x (8 segments).
// ---------------------------------------------------------------------------
__global__ __launch_bounds__(128) void k_gates(
    const float* __restrict__ sents, const float* __restrict__ q_ws,
    const float* __restrict__ mem, const float* __restrict__ gate_w,
    const float* __restrict__ gate_b,
    float* __restrict__ gates_ws, float* __restrict__ gout)
{
    int b = blockIdx.x, tid = threadIdx.x;
    int t = tid >> 3, s = tid & 7;
    float p = 0.f;
    const float* sv = sents + ((size_t)b * NSENT + t) * HDIM;
    for (int jj = 0; jj < 16; jj++) {
        int j = s * 16 + jj;
        float S = sv[j], Q = q_ws[b * HDIM + j], M = mem[b * HDIM + j];
        float dq = S - Q, dm = S - M;
        p += (S * Q) * gate_w[j] + (S * M) * gate_w[HDIM + j] +
             (dq * dq) * gate_w[2 * HDIM + j] + (dm * dm) * gate_w[3 * HDIM + j];
    }
    __shared__ float red[16][8];
    red[t][s] = p;
    __syncthreads();
    if (s == 0) {
        float sum = 0.f;
        for (int k = 0; k < 8; k++) sum += red[t][k];
        float gt = sigmf(sum + gate_b[0]);
        gates_ws[b * NSENT + t] = gt;
        if (gout) gout[b * NSENT + t] = gt;
    }
}

// ---------------------------------------------------------------------------
extern "C" void kernel_launch(void* const* d_in, const int* in_sizes, int n_in,
                              void* d_out, int out_size, void* d_ws, size_t ws_size,
                              hipStream_t stream)
{
    const int*   x_sto    = (const int*)d_in[0];
    const int*   x_mask   = (const int*)d_in[1];
    const int*   x_q      = (const int*)d_in[2];
    const float* emb      = (const float*)d_in[4];
    const float* enc_w_ih = (const float*)d_in[5];
    const float* enc_w_hh = (const float*)d_in[6];
    const float* enc_b_ih = (const float*)d_in[7];
    const float* enc_b_hh = (const float*)d_in[8];
    const float* gate_w   = (const float*)d_in[9];
    const float* gate_b   = (const float*)d_in[10];
    const float* ep_w_ih  = (const float*)d_in[11];
    const float* ep_w_hh  = (const float*)d_in[12];
    const float* ep_b_ih  = (const float*)d_in[13];
    const float* ep_b_hh  = (const float*)d_in[14];

    float* out_q  = (float*)d_out;                       // (64,128)
    float* out_ep = (float*)d_out + BATCH * HDIM;        // (1,64,128)
    float* out_g  = (float*)d_out + 2 * BATCH * HDIM;    // (64,16)

    char* ws = (char*)d_ws;
    size_t off = 0;
    auto alloc = [&](size_t bytes) {
        void* p = ws + off;
        off += (bytes + 255) & ~(size_t)255;
        return p;
    };
    __hip_bfloat16* gi_sto = (__hip_bfloat16*)alloc((size_t)BATCH * LSTO * G3 * 2);
    __hip_bfloat16* gi_q   = (__hip_bfloat16*)alloc((size_t)BATCH * QLEN * G3 * 2);
    __hip_bfloat16* gi_ep  = (__hip_bfloat16*)alloc((size_t)BATCH * NSENT * G3 * 2);
    float* sents    = (float*)alloc((size_t)BATCH * NSENT * HDIM * 4);
    float* q_ws     = (float*)alloc((size_t)BATCH * HDIM * 4);
    float* mem      = (float*)alloc((size_t)BATCH * HDIM * 4);
    float* gates_ws = (float*)alloc((size_t)BATCH * NSENT * 4);
    (void)ws_size; (void)in_sizes; (void)n_in; (void)out_size;

    // Phase A: input-projection GEMMs (gather + matmul), bf16 output
    k_gi_gather<<<(BATCH * LSTO) / 32, 192, 0, stream>>>(
        x_sto, BATCH * LSTO, emb, enc_w_ih, enc_b_ih, gi_sto);
    k_gi_gather<<<(BATCH * QLEN) / 32, 192, 0, stream>>>(
        x_q, BATCH * QLEN, emb, enc_w_ih, enc_b_ih, gi_q);

    // Phase B: story scan (writes sents), question scan (writes q_vecs)
    k_scan<0><<<BATCH, 192, 0, stream>>>(
        gi_sto, LSTO, enc_w_hh, enc_b_hh,
        x_mask, sents, nullptr, nullptr, nullptr, nullptr, nullptr, nullptr);
    k_scan<1><<<BATCH, 192, 0, stream>>>(
        gi_q, QLEN, enc_w_hh, enc_b_hh,
        nullptr, nullptr, x_q, out_q, q_ws, nullptr, nullptr, nullptr);

    // Phase C: episodic memory, 3 iterations
    k_gi_dense<<<(BATCH * NSENT) / 32, 192, 0, stream>>>(
        sents, BATCH * NSENT, ep_w_ih, ep_b_ih, gi_ep);

    for (int it = 0; it < 3; ++it) {
        const float* msrc = (it == 0) ? q_ws : mem;
        k_gates<<<BATCH, 128, 0, stream>>>(
            sents, q_ws, msrc, gate_w, gate_b, gates_ws,
            (it == 2) ? out_g : nullptr);
        k_scan<2><<<BATCH, 192, 0, stream>>>(
            gi_ep, NSENT, ep_w_hh, ep_b_hh,
            nullptr, nullptr, nullptr, nullptr, nullptr,
            gates_ws, mem, (it == 2) ? out_ep : nullptr);
    }
}

// Round 5
// 1870.209 us; speedup vs baseline: 1.7029x; 1.7029x over previous
//
#include <hip/hip_runtime.h>
#include <hip/hip_bf16.h>

#define HDIM 128
#define G3 384          // 3*H
#define EDIM 300
#define BATCH 64
#define LSTO 1024
#define QLEN 32
#define NSENT 16

typedef float4 f4;

__device__ __forceinline__ float sigmf(float x) { return 1.0f / (1.0f + __expf(-x)); }
__device__ __forceinline__ float tanhfast(float x) {
    float e = __expf(-2.0f * x);
    return (1.0f - e) / (1.0f + e);
}

// ---------------------------------------------------------------------------
// K1: gi[row][g] = b_ih[g] + emb[tok[row]] . w_ih[g]   (K = 300), bf16 out
// 32 rows per WG staged in LDS; 192 threads, each handles g and g+192.
// ---------------------------------------------------------------------------
__global__ __launch_bounds__(192) void k_gi_gather(
    const int* __restrict__ toks, int nrows,
    const float* __restrict__ emb,
    const float* __restrict__ w_ih, const float* __restrict__ b_ih,
    __hip_bfloat16* __restrict__ gi)
{
    __shared__ alignas(16) float a_lds[32 * EDIM];
    int tid = threadIdx.x;
    int rowbase = blockIdx.x * 32;

    for (int i = tid; i < 32 * 75; i += 192) {   // 75 = 300/4
        int r = i / 75, e4 = i - r * 75;
        int row = rowbase + r;
        int tok = (row < nrows) ? toks[row] : 0;
        f4 v = *reinterpret_cast<const f4*>(emb + (size_t)tok * EDIM + e4 * 4);
        *reinterpret_cast<f4*>(a_lds + r * EDIM + e4 * 4) = v;
    }
    __syncthreads();

    int g0 = tid, g1 = tid + 192;
    float acc0[32], acc1[32];
#pragma unroll
    for (int r = 0; r < 32; r++) { acc0[r] = 0.f; acc1[r] = 0.f; }

    const float* w0p = w_ih + (size_t)g0 * EDIM;
    const float* w1p = w_ih + (size_t)g1 * EDIM;
    for (int e4 = 0; e4 < 75; ++e4) {
        f4 w0 = *reinterpret_cast<const f4*>(w0p + e4 * 4);
        f4 w1 = *reinterpret_cast<const f4*>(w1p + e4 * 4);
#pragma unroll
        for (int r = 0; r < 32; r++) {
            f4 a = *reinterpret_cast<const f4*>(a_lds + r * EDIM + e4 * 4);
            acc0[r] += a.x * w0.x + a.y * w0.y + a.z * w0.z + a.w * w0.w;
            acc1[r] += a.x * w1.x + a.y * w1.y + a.z * w1.z + a.w * w1.w;
        }
    }
    float bb0 = b_ih[g0], bb1 = b_ih[g1];
    for (int r = 0; r < 32; r++) {
        int row = rowbase + r;
        if (row < nrows) {
            gi[(size_t)row * G3 + g0] = __float2bfloat16(acc0[r] + bb0);
            gi[(size_t)row * G3 + g1] = __float2bfloat16(acc1[r] + bb1);
        }
    }
}

// ---------------------------------------------------------------------------
// K1b: dense variant, K = 128 (episodic gi from sents)
// ---------------------------------------------------------------------------
__global__ __launch_bounds__(192) void k_gi_dense(
    const float* __restrict__ x, int nrows,
    const float* __restrict__ w_ih, const float* __restrict__ b_ih,
    __hip_bfloat16* __restrict__ gi)
{
    __shared__ alignas(16) float a_lds[32 * HDIM];
    int tid = threadIdx.x;
    int rowbase = blockIdx.x * 32;

    for (int i = tid; i < 32 * 32; i += 192) {   // 32 = 128/4
        int r = i >> 5, e4 = i & 31;
        int row = rowbase + r;
        f4 v;
        if (row < nrows) v = *reinterpret_cast<const f4*>(x + (size_t)row * HDIM + e4 * 4);
        else { v.x = v.y = v.z = v.w = 0.f; }
        *reinterpret_cast<f4*>(a_lds + r * HDIM + e4 * 4) = v;
    }
    __syncthreads();

    int g0 = tid, g1 = tid + 192;
    float acc0[32], acc1[32];
#pragma unroll
    for (int r = 0; r < 32; r++) { acc0[r] = 0.f; acc1[r] = 0.f; }

    const float* w0p = w_ih + (size_t)g0 * HDIM;
    const float* w1p = w_ih + (size_t)g1 * HDIM;
    for (int e4 = 0; e4 < 32; ++e4) {
        f4 w0 = *reinterpret_cast<const f4*>(w0p + e4 * 4);
        f4 w1 = *reinterpret_cast<const f4*>(w1p + e4 * 4);
#pragma unroll
        for (int r = 0; r < 32; r++) {
            f4 a = *reinterpret_cast<const f4*>(a_lds + r * HDIM + e4 * 4);
            acc0[r] += a.x * w0.x + a.y * w0.y + a.z * w0.z + a.w * w0.w;
            acc1[r] += a.x * w1.x + a.y * w1.y + a.z * w1.z + a.w * w1.w;
        }
    }
    float bb0 = b_ih[g0], bb1 = b_ih[g1];
    for (int r = 0; r < 32; r++) {
        int row = rowbase + r;
        if (row < nrows) {
            gi[(size_t)row * G3 + g0] = __float2bfloat16(acc0[r] + bb0);
            gi[(size_t)row * G3 + g1] = __float2bfloat16(acc1[r] + bb1);
        }
    }
}

// ---------------------------------------------------------------------------
// K2: sequential GRU scan, one workgroup per batch element.
// 384 threads (6 waves); thread g holds w_hh row g in 128 VGPRs (no spill).
// Per step: [prefetch gi for this step] -> dot(h, w) -> gh_lds -> barrier ->
//           elementwise update by threads 0..127 -> barrier.
// MODE 0: stories (write sents at masked positions)
// MODE 1: questions (write q_vec at position qi)
// MODE 2: episodic (gate-interpolated update, write final h)
// ---------------------------------------------------------------------------
template <int MODE>
__global__ __launch_bounds__(384, 1) void k_scan(
    const __hip_bfloat16* __restrict__ gi,   // [BATCH*T][384]
    int T,
    const float* __restrict__ w_hh, const float* __restrict__ b_hh,
    const int* __restrict__ mask,            // MODE 0
    float* __restrict__ sents,               // MODE 0
    const int* __restrict__ qtoks,           // MODE 1
    float* __restrict__ qv_out,              // MODE 1 (d_out)
    float* __restrict__ q_ws,                // MODE 1
    const float* __restrict__ gates,         // MODE 2
    float* __restrict__ h_out,               // MODE 2 (mem ws)
    float* __restrict__ ep_out)              // MODE 2 (d_out, nullable)
{
    __shared__ alignas(16) float h_lds[HDIM];
    __shared__ float gh_lds[G3];

    int tid = threadIdx.x;          // 0..383, = output gate index g
    int b = blockIdx.x;

    // one w_hh row per thread: 128 f32 VGPRs
    float w[HDIM];
#pragma unroll
    for (int k4 = 0; k4 < 32; k4++) {
        f4 a = *reinterpret_cast<const f4*>(w_hh + (size_t)tid * HDIM + k4 * 4);
        w[4 * k4 + 0] = a.x; w[4 * k4 + 1] = a.y;
        w[4 * k4 + 2] = a.z; w[4 * k4 + 3] = a.w;
    }
    float bb = b_hh[tid];

    if (tid < HDIM) h_lds[tid] = 0.f;

    int qi = QLEN - 1;
    if (MODE == 1) {
        for (int t2 = QLEN - 2; t2 >= 0; --t2)
            if (qtoks[b * QLEN + t2 + 1] == 0) qi = t2;
    }
    int scnt = 0;
    __syncthreads();

    const __hip_bfloat16* gib = gi + (size_t)b * T * G3;

    for (int t = 0; t < T; ++t) {
        // ---- phase 0: issue this step's gi (+mask/gate) loads, raw regs ----
        __hip_bfloat16 gr_r, gr_z, gr_n;
        int m = 0;
        float wgate = 0.f;
        if (tid < HDIM) {
            const __hip_bfloat16* gr = gib + (size_t)t * G3;
            gr_r = gr[tid];
            gr_z = gr[HDIM + tid];
            gr_n = gr[2 * HDIM + tid];
            if (MODE == 0) m = mask[b * LSTO + t];
            if (MODE == 2) wgate = gates[b * NSENT + t];
        }

        // ---- phase 1: gh[g] = bb + h . w  (4 partial accumulators) ----
        float a0 = bb, a1 = 0.f, a2 = 0.f, a3 = 0.f;
#pragma unroll
        for (int k16 = 0; k16 < 8; ++k16) {
            f4 h0 = *reinterpret_cast<const f4*>(h_lds + k16 * 16 + 0);
            f4 h1 = *reinterpret_cast<const f4*>(h_lds + k16 * 16 + 4);
            f4 h2 = *reinterpret_cast<const f4*>(h_lds + k16 * 16 + 8);
            f4 h3 = *reinterpret_cast<const f4*>(h_lds + k16 * 16 + 12);
            a0 += h0.x * w[k16 * 16 + 0] + h0.y * w[k16 * 16 + 1] +
                  h0.z * w[k16 * 16 + 2] + h0.w * w[k16 * 16 + 3];
            a1 += h1.x * w[k16 * 16 + 4] + h1.y * w[k16 * 16 + 5] +
                  h1.z * w[k16 * 16 + 6] + h1.w * w[k16 * 16 + 7];
            a2 += h2.x * w[k16 * 16 + 8] + h2.y * w[k16 * 16 + 9] +
                  h2.z * w[k16 * 16 + 10] + h2.w * w[k16 * 16 + 11];
            a3 += h3.x * w[k16 * 16 + 12] + h3.y * w[k16 * 16 + 13] +
                  h3.z * w[k16 * 16 + 14] + h3.w * w[k16 * 16 + 15];
        }
        gh_lds[tid] = (a0 + a1) + (a2 + a3);
        __syncthreads();

        // ---- phase 2: elementwise GRU cell on threads 0..127 ----
        if (tid < HDIM) {
            int j = tid;
            float r = sigmf(__bfloat162float(gr_r) + gh_lds[j]);
            float z = sigmf(__bfloat162float(gr_z) + gh_lds[HDIM + j]);
            float n = tanhfast(__bfloat162float(gr_n) + r * gh_lds[2 * HDIM + j]);
            float hprev = h_lds[j];
            float hn = (1.f - z) * n + z * hprev;
            if (MODE == 2) {
                hn = wgate * hn + (1.f - wgate) * hprev;
            }
            h_lds[j] = hn;

            if (MODE == 0) {
                if (m) {
                    if (scnt < NSENT)
                        sents[((size_t)b * NSENT + scnt) * HDIM + j] = hn;
                    scnt++;
                }
            }
            if (MODE == 1 && t == qi) {
                qv_out[b * HDIM + j] = hn;
                q_ws[b * HDIM + j] = hn;
            }
            if (MODE == 2 && t == T - 1) {
                h_out[b * HDIM + j] = hn;
                if (ep_out) ep_out[b * HDIM + j] = hn;
            }
        }
        __syncthreads();
    }
}

// ---------------------------------------------------------------------------
// K3: attention gates.  WG per batch, 128 threads = (16 t) x (8 segments).
// ---------------------------------------------------------------------------
__global__ __launch_bounds__(128) void k_gates(
    const float* __restrict__ sents, const float* __restrict__ q_ws,
    const float* __restrict__ mem, const float* __restrict__ gate_w,
    const float* __restrict__ gate_b,
    float* __restrict__ gates_ws, float* __restrict__ gout)
{
    int b = blockIdx.x, tid = threadIdx.x;
    int t = tid >> 3, s = tid & 7;
    float p = 0.f;
    const float* sv = sents + ((size_t)b * NSENT + t) * HDIM;
    for (int jj = 0; jj < 16; jj++) {
        int j = s * 16 + jj;
        float S = sv[j], Q = q_ws[b * HDIM + j], M = mem[b * HDIM + j];
        float dq = S - Q, dm = S - M;
        p += (S * Q) * gate_w[j] + (S * M) * gate_w[HDIM + j] +
             (dq * dq) * gate_w[2 * HDIM + j] + (dm * dm) * gate_w[3 * HDIM + j];
    }
    __shared__ float red[16][8];
    red[t][s] = p;
    __syncthreads();
    if (s == 0) {
        float sum = 0.f;
        for (int k = 0; k < 8; k++) sum += red[t][k];
        float gt = sigmf(sum + gate_b[0]);
        gates_ws[b * NSENT + t] = gt;
        if (gout) gout[b * NSENT + t] = gt;
    }
}

// ---------------------------------------------------------------------------
extern "C" void kernel_launch(void* const* d_in, const int* in_sizes, int n_in,
                              void* d_out, int out_size, void* d_ws, size_t ws_size,
                              hipStream_t stream)
{
    const int*   x_sto    = (const int*)d_in[0];
    const int*   x_mask   = (const int*)d_in[1];
    const int*   x_q      = (const int*)d_in[2];
    const float* emb      = (const float*)d_in[4];
    const float* enc_w_ih = (const float*)d_in[5];
    const float* enc_w_hh = (const float*)d_in[6];
    const float* enc_b_ih = (const float*)d_in[7];
    const float* enc_b_hh = (const float*)d_in[8];
    const float* gate_w   = (const float*)d_in[9];
    const float* gate_b   = (const float*)d_in[10];
    const float* ep_w_ih  = (const float*)d_in[11];
    const float* ep_w_hh  = (const float*)d_in[12];
    const float* ep_b_ih  = (const float*)d_in[13];
    const float* ep_b_hh  = (const float*)d_in[14];

    float* out_q  = (float*)d_out;                       // (64,128)
    float* out_ep = (float*)d_out + BATCH * HDIM;        // (1,64,128)
    float* out_g  = (float*)d_out + 2 * BATCH * HDIM;    // (64,16)

    char* ws = (char*)d_ws;
    size_t off = 0;
    auto alloc = [&](size_t bytes) {
        void* p = ws + off;
        off += (bytes + 255) & ~(size_t)255;
        return p;
    };
    __hip_bfloat16* gi_sto = (__hip_bfloat16*)alloc((size_t)BATCH * LSTO * G3 * 2);
    __hip_bfloat16* gi_q   = (__hip_bfloat16*)alloc((size_t)BATCH * QLEN * G3 * 2);
    __hip_bfloat16* gi_ep  = (__hip_bfloat16*)alloc((size_t)BATCH * NSENT * G3 * 2);
    float* sents    = (float*)alloc((size_t)BATCH * NSENT * HDIM * 4);
    float* q_ws     = (float*)alloc((size_t)BATCH * HDIM * 4);
    float* mem      = (float*)alloc((size_t)BATCH * HDIM * 4);
    float* gates_ws = (float*)alloc((size_t)BATCH * NSENT * 4);
    (void)ws_size; (void)in_sizes; (void)n_in; (void)out_size;

    // Phase A: input-projection GEMMs (gather + matmul), bf16 output
    k_gi_gather<<<(BATCH * LSTO) / 32, 192, 0, stream>>>(
        x_sto, BATCH * LSTO, emb, enc_w_ih, enc_b_ih, gi_sto);
    k_gi_gather<<<(BATCH * QLEN) / 32, 192, 0, stream>>>(
        x_q, BATCH * QLEN, emb, enc_w_ih, enc_b_ih, gi_q);

    // Phase B: story scan (writes sents), question scan (writes q_vecs)
    k_scan<0><<<BATCH, 384, 0, stream>>>(
        gi_sto, LSTO, enc_w_hh, enc_b_hh,
        x_mask, sents, nullptr, nullptr, nullptr, nullptr, nullptr, nullptr);
    k_scan<1><<<BATCH, 384, 0, stream>>>(
        gi_q, QLEN, enc_w_hh, enc_b_hh,
        nullptr, nullptr, x_q, out_q, q_ws, nullptr, nullptr, nullptr);

    // Phase C: episodic memory, 3 iterations
    k_gi_dense<<<(BATCH * NSENT) / 32, 192, 0, stream>>>(
        sents, BATCH * NSENT, ep_w_ih, ep_b_ih, gi_ep);

    for (int it = 0; it < 3; ++it) {
        const float* msrc = (it == 0) ? q_ws : mem;
        k_gates<<<BATCH, 128, 0, stream>>>(
            sents, q_ws, msrc, gate_w, gate_b, gates_ws,
            (it == 2) ? out_g : nullptr);
        k_scan<2><<<BATCH, 384, 0, stream>>>(
            gi_ep, NSENT, ep_w_hh, ep_b_hh,
            nullptr, nullptr, nullptr, nullptr, nullptr,
            gates_ws, mem, (it == 2) ? out_ep : nullptr);
    }
}